// Round 1
// 884.844 us; speedup vs baseline: 1.0289x; 1.0289x over previous
//
#include <hip/hip_runtime.h>
#include <hip/hip_fp16.h>
#include <stdint.h>

typedef _Float16 f16x8 __attribute__((ext_vector_type(8)));
typedef __fp16 h16x2 __attribute__((ext_vector_type(2)));
typedef float f32x4 __attribute__((ext_vector_type(4)));

#define NH   16
#define DK   64
#define SEQ  2048
#define HID  1024
#define MTOT 4096   // B*S

__device__ __forceinline__ ushort f2h_bits(float f) {
  union { __half h; ushort u; } cv;
  cv.h = __float2half(f);
  return cv.u;
}

__device__ __forceinline__ void lds_load16(const void* g, void* l) {
  __builtin_amdgcn_global_load_lds((const __attribute__((address_space(1))) uint32_t*)g,
                                   (__attribute__((address_space(3))) uint32_t*)l, 16, 0, 0);
}

__device__ __forceinline__ f16x8 cvt8(float4 v0, float4 v1) {
  union { f16x8 v; h16x2 p[4]; } u;
  u.p[0] = __builtin_amdgcn_cvt_pkrtz(v0.x, v0.y);
  u.p[1] = __builtin_amdgcn_cvt_pkrtz(v0.z, v0.w);
  u.p[2] = __builtin_amdgcn_cvt_pkrtz(v1.x, v1.y);
  u.p[3] = __builtin_amdgcn_cvt_pkrtz(v1.z, v1.w);
  return u.v;
}

// ---------------- NT GEMM: Y[m,n] = sum_k A[m,k]*W[n,k] + bias[n] ----------------
// 128x128 tile, BK=64, 4 waves (2x2), each wave 64x64 via 4x4 MFMA 16x16x32 f16.
// LDS layout XOR-swizzled: LDS[row][c] = SRC[row][c ^ (row&7)] -> conflict-light ds_read_b128.
// AF32/BF32: stage fp32 source via float4 loads + cvt_pkrtz + ds_write_b128.
// mode 0: f16 out head-split [b,h,s,d]; mode 1: f32 row-major; mode 2: f16 [b,h,d,s] (V transposed).
template <bool AF32, bool BF32>
__device__ __forceinline__ void gemm_body(int mode, const void* __restrict__ Ap, const void* __restrict__ Bp,
                                          const float* __restrict__ bias, void* __restrict__ Out) {
  constexpr int K = 1024, N = 1024;
  __shared__ ushort As[128 * 64];
  __shared__ ushort Bs[128 * 64];
  const int tid = threadIdx.x;
  const int lane = tid & 63;
  const int w = tid >> 6;
  const int wr = w >> 1, wc = w & 1;
  const int bM = blockIdx.y * 128, bN = blockIdx.x * 128;
  const int srow = lane >> 3;                // row within 8-row group
  const int c8 = lane & 7;                   // chunk within row
  const int schunk = (c8 ^ srow) * 8;        // swizzled source chunk (elements)
  const int l15 = lane & 15, quad = lane >> 4;

  f32x4 acc[4][4];
#pragma unroll
  for (int i = 0; i < 4; ++i)
#pragma unroll
    for (int j = 0; j < 4; ++j) acc[i][j] = f32x4{0.f, 0.f, 0.f, 0.f};

  for (int k0 = 0; k0 < K; k0 += 64) {
#pragma unroll
    for (int j = 0; j < 4; ++j) {
      const int row = w * 32 + j * 8 + srow;
      if (AF32) {
        const float* src = (const float*)Ap + (size_t)(bM + row) * K + k0 + schunk;
        float4 v0 = *(const float4*)src;
        float4 v1 = *(const float4*)(src + 4);
        *(f16x8*)&As[row * 64 + c8 * 8] = cvt8(v0, v1);
      } else {
        lds_load16((const ushort*)Ap + (size_t)(bM + w * 32 + srow) * K + k0 + schunk + (size_t)(j * 8) * K,
                   &As[(w * 32 + j * 8) * 64]);
      }
      if (BF32) {
        const float* src = (const float*)Bp + (size_t)(bN + row) * K + k0 + schunk;
        float4 v0 = *(const float4*)src;
        float4 v1 = *(const float4*)(src + 4);
        *(f16x8*)&Bs[row * 64 + c8 * 8] = cvt8(v0, v1);
      } else {
        lds_load16((const ushort*)Bp + (size_t)(bN + w * 32 + srow) * K + k0 + schunk + (size_t)(j * 8) * K,
                   &Bs[(w * 32 + j * 8) * 64]);
      }
    }
    __syncthreads();
#pragma unroll
    for (int ks = 0; ks < 2; ++ks) {
      const int q = ks * 4 + quad;
      f16x8 af[4], bfr[4];
#pragma unroll
      for (int i = 0; i < 4; ++i) {
        const int m = wr * 64 + i * 16 + l15;
        af[i] = *(const f16x8*)&As[m * 64 + ((q ^ (m & 7)) * 8)];
        const int n = wc * 64 + i * 16 + l15;
        bfr[i] = *(const f16x8*)&Bs[n * 64 + ((q ^ (n & 7)) * 8)];
      }
#pragma unroll
      for (int i = 0; i < 4; ++i)
#pragma unroll
        for (int j = 0; j < 4; ++j)
          acc[i][j] = __builtin_amdgcn_mfma_f32_16x16x32_f16(af[i], bfr[j], acc[i][j], 0, 0, 0);
    }
    __syncthreads();
  }

  if (mode == 1) {
    float* O = (float*)Out;
#pragma unroll
    for (int j = 0; j < 4; ++j) {
      const int n = bN + wc * 64 + j * 16 + l15;
      const float bv = bias[n];
#pragma unroll
      for (int i = 0; i < 4; ++i) {
        const int mbase = bM + wr * 64 + i * 16 + quad * 4;
#pragma unroll
        for (int r = 0; r < 4; ++r)
          O[(size_t)(mbase + r) * N + n] = acc[i][j][r] + bv;
      }
    }
  } else if (mode == 0) {
    ushort* O = (ushort*)Out;
#pragma unroll
    for (int j = 0; j < 4; ++j) {
      const int n = bN + wc * 64 + j * 16 + l15;
      const int h = n >> 6, d = n & 63;
      const float bv = bias[n];
#pragma unroll
      for (int i = 0; i < 4; ++i) {
        const int mbase = bM + wr * 64 + i * 16 + quad * 4;
        const int b = mbase >> 11;
#pragma unroll
        for (int r = 0; r < 4; ++r) {
          const int s = (mbase + r) & 2047;
          O[((size_t)((b * NH + h) * SEQ + s)) * DK + d] = f2h_bits(acc[i][j][r] + bv);
        }
      }
    }
  } else {  // mode 2: V transposed [b,h,d,s]
    ushort* O = (ushort*)Out;
#pragma unroll
    for (int j = 0; j < 4; ++j) {
      const int n = bN + wc * 64 + j * 16 + l15;
      const int h = n >> 6, d = n & 63;
      const float bv = bias[n];
#pragma unroll
      for (int i = 0; i < 4; ++i) {
        const int mbase = bM + wr * 64 + i * 16 + quad * 4;
        const int b = mbase >> 11, s = mbase & 2047;
        ushort4 o;
        o.x = f2h_bits(acc[i][j][0] + bv);
        o.y = f2h_bits(acc[i][j][1] + bv);
        o.z = f2h_bits(acc[i][j][2] + bv);
        o.w = f2h_bits(acc[i][j][3] + bv);
        *(ushort4*)&O[((size_t)((b * NH + h) * DK + d)) * SEQ + s] = o;
      }
    }
  }
}

__global__ __launch_bounds__(256) void gemm_qkv(const float* q, const float* k, const float* v,
                                                const float* wq, const float* wk, const float* wv,
                                                const float* bq, const float* bk, const float* bv,
                                                ushort* oq, ushort* ok, ushort* ov) {
  const int z = blockIdx.z;
  const float* A = z == 0 ? q : (z == 1 ? k : v);
  const float* W = z == 0 ? wq : (z == 1 ? wk : wv);
  const float* bb = z == 0 ? bq : (z == 1 ? bk : bv);
  ushort* O = z == 0 ? oq : (z == 1 ? ok : ov);
  gemm_body<true, true>(z == 2 ? 2 : 0, A, W, bb, O);
}

__global__ __launch_bounds__(256) void gemm_out(const ushort* A, const float* W, const float* b, float* O) {
  gemm_body<false, true>(1, A, W, b, O);
}

// ---------------- attention ----------------
// block = (bh, 16 q-rows), 512 threads = 8 waves; wave w owns K-cols [w*256, w*256+256).
// Scores strip 16x256 per wave in registers (sc[16] = 64 VGPRs).
// __launch_bounds__(512, 4): cap VGPR at 128 -> 2 blocks/CU so barriers + the vmcnt(0)
// drain of the 64 nontemporal P-stores overlap with the co-resident block.
__global__ __launch_bounds__(512, 4) void attn_kernel(const ushort* __restrict__ Qh, const ushort* __restrict__ Kh,
                                                      const ushort* __restrict__ Vt, float* __restrict__ P,
                                                      ushort* __restrict__ Xm) {
  const int bh = blockIdx.y;       // 0..31
  const int q0 = blockIdx.x * 16;  // q-tile start
  const int tid = threadIdx.x;
  const int lane = tid & 63, w = tid >> 6;
  const int quad = lane >> 4, l15 = lane & 15;
  const int wstart = w * 256;

  const size_t base = (size_t)bh * SEQ * DK;
  const ushort* Qp = Qh + base + (size_t)(q0 + l15) * DK + quad * 8;
  const f16x8 aq0 = *(const f16x8*)Qp;
  const f16x8 aq1 = *(const f16x8*)(Qp + 32);

  // ---- QK^T: 16 x 256 score strip in registers (C layout: row=quad*4+r, col=t*16+l15) ----
  f32x4 sc[16];
#pragma unroll
  for (int t = 0; t < 16; ++t) sc[t] = f32x4{0.f, 0.f, 0.f, 0.f};

  const ushort* Kp = Kh + base + (size_t)(wstart + l15) * DK + quad * 8;
#pragma unroll
  for (int t = 0; t < 16; ++t) {
    const ushort* kp = Kp + (size_t)(t * 16) * DK;
    const f16x8 b0 = *(const f16x8*)kp;
    const f16x8 b1 = *(const f16x8*)(kp + 32);
    sc[t] = __builtin_amdgcn_mfma_f32_16x16x32_f16(aq0, b0, sc[t], 0, 0, 0);
    sc[t] = __builtin_amdgcn_mfma_f32_16x16x32_f16(aq1, b1, sc[t], 0, 0, 0);
  }

  // ---- softmax ----
  __shared__ float redm[8][16];
  __shared__ float reds[8][16];
  constexpr float scale = 0.125f;  // 1/sqrt(64)

  float mrow[4];
#pragma unroll
  for (int r = 0; r < 4; ++r) {
    float v = sc[0][r];
#pragma unroll
    for (int t = 1; t < 16; ++t) v = fmaxf(v, sc[t][r]);
#pragma unroll
    for (int off = 1; off < 16; off <<= 1) v = fmaxf(v, __shfl_xor(v, off));
    if (l15 == 0) redm[w][quad * 4 + r] = v;
  }
  __syncthreads();
#pragma unroll
  for (int r = 0; r < 4; ++r) {
    const int row = quad * 4 + r;
    float m = redm[0][row];
#pragma unroll
    for (int wi = 1; wi < 8; ++wi) m = fmaxf(m, redm[wi][row]);
    mrow[r] = m;
  }
#pragma unroll
  for (int r = 0; r < 4; ++r) {
    float s = 0.f;
#pragma unroll
    for (int t = 0; t < 16; ++t) {
      const float e = __expf((sc[t][r] - mrow[r]) * scale);
      sc[t][r] = e;
      s += e;
    }
#pragma unroll
    for (int off = 1; off < 16; off <<= 1) s += __shfl_xor(s, off);
    if (l15 == 0) reds[w][quad * 4 + r] = s;
  }
  __syncthreads();
  float inv[4];
#pragma unroll
  for (int r = 0; r < 4; ++r) {
    const int row = quad * 4 + r;
    float s = reds[0][row];
#pragma unroll
    for (int wi = 1; wi < 8; ++wi) s += reds[wi][row];
    inv[r] = 1.f / s;
  }

  // ---- p store (nontemporal) + PV accumulate ----
  float* Pb = P + ((size_t)bh * SEQ + q0) * SEQ + wstart;
  __shared__ ushort Pl[8][16 * 40];  // per-wave P chunk in A-frag layout
  const ushort* Vb = Vt + (size_t)bh * DK * SEQ + wstart;
  f32x4 xacc[4];
#pragma unroll
  for (int dt = 0; dt < 4; ++dt) xacc[dt] = f32x4{0.f, 0.f, 0.f, 0.f};

#pragma unroll
  for (int c = 0; c < 8; ++c) {  // 32-col chunks
#pragma unroll
    for (int t2 = 0; t2 < 2; ++t2) {
      const int t = c * 2 + t2;
#pragma unroll
      for (int r = 0; r < 4; ++r) {
        const float p = sc[t][r] * inv[r];
        __builtin_nontemporal_store(p, &Pb[(size_t)(quad * 4 + r) * SEQ + t * 16 + l15]);
        Pl[w][(quad * 4 + r) * 40 + t2 * 16 + l15] = f2h_bits(p);
      }
    }
    const f16x8 pa = *(const f16x8*)&Pl[w][l15 * 40 + quad * 8];
#pragma unroll
    for (int dt = 0; dt < 4; ++dt) {
      const f16x8 bv = *(const f16x8*)(Vb + (size_t)(dt * 16 + l15) * SEQ + c * 32 + quad * 8);
      xacc[dt] = __builtin_amdgcn_mfma_f32_16x16x32_f16(pa, bv, xacc[dt], 0, 0, 0);
    }
  }

  // ---- reduce x across 8 waves, store merged [b,s,h*64+d] f16 ----
  __shared__ float xred[8][16 * 64];  // 32 KB
#pragma unroll
  for (int dt = 0; dt < 4; ++dt)
#pragma unroll
    for (int r = 0; r < 4; ++r)
      xred[w][(quad * 4 + r) * 64 + dt * 16 + l15] = xacc[dt][r];
  __syncthreads();
  {
    const int b = bh >> 4, h = bh & 15;
    const int e0 = tid * 2;
    const int row = e0 >> 6;
    const int d = e0 & 63;
    float s0 = 0.f, s1 = 0.f;
#pragma unroll
    for (int wi = 0; wi < 8; ++wi) {
      s0 += xred[wi][e0];
      s1 += xred[wi][e0 + 1];
    }
    ushort2 o;
    o.x = f2h_bits(s0);
    o.y = f2h_bits(s1);
    *(ushort2*)&Xm[((size_t)(b * SEQ + q0 + row)) * HID + h * DK + d] = o;
  }
}

// ---------------- launch ----------------
extern "C" void kernel_launch(void* const* d_in, const int* in_sizes, int n_in,
                              void* d_out, int out_size, void* d_ws, size_t ws_size,
                              hipStream_t stream) {
  const float* query = (const float*)d_in[0];
  const float* key   = (const float*)d_in[1];
  const float* value = (const float*)d_in[2];
  const float* Wq = (const float*)d_in[3];
  const float* bq = (const float*)d_in[4];
  const float* Wk = (const float*)d_in[5];
  const float* bk = (const float*)d_in[6];
  const float* Wv = (const float*)d_in[7];
  const float* bv = (const float*)d_in[8];
  const float* Wo = (const float*)d_in[9];
  const float* bo = (const float*)d_in[10];

  float* out  = (float*)d_out;
  float* pout = out + (size_t)MTOT * HID;  // p_attn section

  // workspace: exactly 32 MB
  ushort* Qhs = (ushort*)d_ws;             // [b,h,s,d] f16, 8 MB
  ushort* Khs = Qhs + 4194304;             // [b,h,s,d] f16, 8 MB
  ushort* Vtw = Khs + 4194304;             // [b,h,d,s] f16, 8 MB
  ushort* xm  = Vtw + 4194304;             // [b,s,h*64+d] f16, 8 MB

  gemm_qkv<<<dim3(8, 32, 3), 256, 0, stream>>>(query, key, value, Wq, Wk, Wv, bq, bk, bv, Qhs, Khs, Vtw);
  attn_kernel<<<dim3(128, 32), 512, 0, stream>>>(Qhs, Khs, Vtw, pout, xm);
  gemm_out<<<dim3(8, 32), 256, 0, stream>>>(xm, Wo, bo, out);
}

// Round 2
// 883.023 us; speedup vs baseline: 1.0310x; 1.0021x over previous
//
#include <hip/hip_runtime.h>
#include <hip/hip_fp16.h>
#include <stdint.h>

typedef _Float16 f16x8 __attribute__((ext_vector_type(8)));
typedef __fp16 h16x2 __attribute__((ext_vector_type(2)));
typedef float f32x4 __attribute__((ext_vector_type(4)));

#define NH   16
#define DK   64
#define SEQ  2048
#define HID  1024
#define MTOT 4096   // B*S

__device__ __forceinline__ ushort f2h_bits(float f) {
  union { __half h; ushort u; } cv;
  cv.h = __float2half(f);
  return cv.u;
}

__device__ __forceinline__ void lds_load16(const void* g, void* l) {
  __builtin_amdgcn_global_load_lds((const __attribute__((address_space(1))) uint32_t*)g,
                                   (__attribute__((address_space(3))) uint32_t*)l, 16, 0, 0);
}

__device__ __forceinline__ f16x8 cvt8(float4 v0, float4 v1) {
  union { f16x8 v; h16x2 p[4]; } u;
  u.p[0] = __builtin_amdgcn_cvt_pkrtz(v0.x, v0.y);
  u.p[1] = __builtin_amdgcn_cvt_pkrtz(v0.z, v0.w);
  u.p[2] = __builtin_amdgcn_cvt_pkrtz(v1.x, v1.y);
  u.p[3] = __builtin_amdgcn_cvt_pkrtz(v1.z, v1.w);
  return u.v;
}

// ---------------- NT GEMM: Y[m,n] = sum_k A[m,k]*W[n,k] + bias[n] ----------------
// 128x128 tile, BK=64, 4 waves (2x2), each wave 64x64 via 4x4 MFMA 16x16x32 f16.
// LDS layout XOR-swizzled: LDS[row][c] = SRC[row][c ^ (row&7)] -> conflict-light ds_read_b128.
// AF32/BF32: stage fp32 source via float4 loads + cvt_pkrtz + ds_write_b128.
// mode 0: f16 out head-split [b,h,s,d]; mode 1: f32 row-major; mode 2: f16 [b,h,d,s] (V transposed).
template <bool AF32, bool BF32>
__device__ __forceinline__ void gemm_body(int mode, const void* __restrict__ Ap, const void* __restrict__ Bp,
                                          const float* __restrict__ bias, void* __restrict__ Out) {
  constexpr int K = 1024, N = 1024;
  __shared__ ushort As[128 * 64];
  __shared__ ushort Bs[128 * 64];
  const int tid = threadIdx.x;
  const int lane = tid & 63;
  const int w = tid >> 6;
  const int wr = w >> 1, wc = w & 1;
  const int bM = blockIdx.y * 128, bN = blockIdx.x * 128;
  const int srow = lane >> 3;                // row within 8-row group
  const int c8 = lane & 7;                   // chunk within row
  const int schunk = (c8 ^ srow) * 8;        // swizzled source chunk (elements)
  const int l15 = lane & 15, quad = lane >> 4;

  f32x4 acc[4][4];
#pragma unroll
  for (int i = 0; i < 4; ++i)
#pragma unroll
    for (int j = 0; j < 4; ++j) acc[i][j] = f32x4{0.f, 0.f, 0.f, 0.f};

  for (int k0 = 0; k0 < K; k0 += 64) {
#pragma unroll
    for (int j = 0; j < 4; ++j) {
      const int row = w * 32 + j * 8 + srow;
      if (AF32) {
        const float* src = (const float*)Ap + (size_t)(bM + row) * K + k0 + schunk;
        float4 v0 = *(const float4*)src;
        float4 v1 = *(const float4*)(src + 4);
        *(f16x8*)&As[row * 64 + c8 * 8] = cvt8(v0, v1);
      } else {
        lds_load16((const ushort*)Ap + (size_t)(bM + w * 32 + srow) * K + k0 + schunk + (size_t)(j * 8) * K,
                   &As[(w * 32 + j * 8) * 64]);
      }
      if (BF32) {
        const float* src = (const float*)Bp + (size_t)(bN + row) * K + k0 + schunk;
        float4 v0 = *(const float4*)src;
        float4 v1 = *(const float4*)(src + 4);
        *(f16x8*)&Bs[row * 64 + c8 * 8] = cvt8(v0, v1);
      } else {
        lds_load16((const ushort*)Bp + (size_t)(bN + w * 32 + srow) * K + k0 + schunk + (size_t)(j * 8) * K,
                   &Bs[(w * 32 + j * 8) * 64]);
      }
    }
    __syncthreads();
#pragma unroll
    for (int ks = 0; ks < 2; ++ks) {
      const int q = ks * 4 + quad;
      f16x8 af[4], bfr[4];
#pragma unroll
      for (int i = 0; i < 4; ++i) {
        const int m = wr * 64 + i * 16 + l15;
        af[i] = *(const f16x8*)&As[m * 64 + ((q ^ (m & 7)) * 8)];
        const int n = wc * 64 + i * 16 + l15;
        bfr[i] = *(const f16x8*)&Bs[n * 64 + ((q ^ (n & 7)) * 8)];
      }
#pragma unroll
      for (int i = 0; i < 4; ++i)
#pragma unroll
        for (int j = 0; j < 4; ++j)
          acc[i][j] = __builtin_amdgcn_mfma_f32_16x16x32_f16(af[i], bfr[j], acc[i][j], 0, 0, 0);
    }
    __syncthreads();
  }

  if (mode == 1) {
    float* O = (float*)Out;
#pragma unroll
    for (int j = 0; j < 4; ++j) {
      const int n = bN + wc * 64 + j * 16 + l15;
      const float bv = bias[n];
#pragma unroll
      for (int i = 0; i < 4; ++i) {
        const int mbase = bM + wr * 64 + i * 16 + quad * 4;
#pragma unroll
        for (int r = 0; r < 4; ++r)
          O[(size_t)(mbase + r) * N + n] = acc[i][j][r] + bv;
      }
    }
  } else if (mode == 0) {
    ushort* O = (ushort*)Out;
#pragma unroll
    for (int j = 0; j < 4; ++j) {
      const int n = bN + wc * 64 + j * 16 + l15;
      const int h = n >> 6, d = n & 63;
      const float bv = bias[n];
#pragma unroll
      for (int i = 0; i < 4; ++i) {
        const int mbase = bM + wr * 64 + i * 16 + quad * 4;
        const int b = mbase >> 11;
#pragma unroll
        for (int r = 0; r < 4; ++r) {
          const int s = (mbase + r) & 2047;
          O[((size_t)((b * NH + h) * SEQ + s)) * DK + d] = f2h_bits(acc[i][j][r] + bv);
        }
      }
    }
  } else {  // mode 2: V transposed [b,h,d,s]
    ushort* O = (ushort*)Out;
#pragma unroll
    for (int j = 0; j < 4; ++j) {
      const int n = bN + wc * 64 + j * 16 + l15;
      const int h = n >> 6, d = n & 63;
      const float bv = bias[n];
#pragma unroll
      for (int i = 0; i < 4; ++i) {
        const int mbase = bM + wr * 64 + i * 16 + quad * 4;
        const int b = mbase >> 11, s = mbase & 2047;
        ushort4 o;
        o.x = f2h_bits(acc[i][j][0] + bv);
        o.y = f2h_bits(acc[i][j][1] + bv);
        o.z = f2h_bits(acc[i][j][2] + bv);
        o.w = f2h_bits(acc[i][j][3] + bv);
        *(ushort4*)&O[((size_t)((b * NH + h) * DK + d)) * SEQ + s] = o;
      }
    }
  }
}

__global__ __launch_bounds__(256) void gemm_qkv(const float* q, const float* k, const float* v,
                                                const float* wq, const float* wk, const float* wv,
                                                const float* bq, const float* bk, const float* bv,
                                                ushort* oq, ushort* ok, ushort* ov) {
  const int z = blockIdx.z;
  const float* A = z == 0 ? q : (z == 1 ? k : v);
  const float* W = z == 0 ? wq : (z == 1 ? wk : wv);
  const float* bb = z == 0 ? bq : (z == 1 ? bk : bv);
  ushort* O = z == 0 ? oq : (z == 1 ? ok : ov);
  gemm_body<true, true>(z == 2 ? 2 : 0, A, W, bb, O);
}

__global__ __launch_bounds__(256) void gemm_out(const ushort* A, const float* W, const float* b, float* O) {
  gemm_body<false, true>(1, A, W, b, O);
}

// ---------------- attention ----------------
// block = (bh, 16 q-rows), 512 threads = 8 waves; wave w owns K-cols [w*256, w*256+256).
// Scores strip 16x256 per wave in registers (sc[16] = 64 VGPRs).
// XCD-aware work remap (T1): hardware dispatches linear block id round-robin across the
// 8 XCDs; work_id = bh*128+qtile is data-contiguous (128 q-tiles share one head's K/V,
// 512 KB). Chunked bijection work = (lin%8)*512 + lin/8 gives each XCD 4 contiguous
// heads -> 2 MB K/V working set inside its 4 MB L2 instead of 16 MB thrash via LLC.
__global__ __launch_bounds__(512, 4) void attn_kernel(const ushort* __restrict__ Qh, const ushort* __restrict__ Kh,
                                                      const ushort* __restrict__ Vt, float* __restrict__ P,
                                                      ushort* __restrict__ Xm) {
  const int lin = blockIdx.y * 128 + blockIdx.x;   // hardware dispatch order
  const int work = (lin & 7) * 512 + (lin >> 3);   // chunked per-XCD remap (bijective, 4096%8==0)
  const int bh = work >> 7;        // 0..31
  const int q0 = (work & 127) * 16;  // q-tile start
  const int tid = threadIdx.x;
  const int lane = tid & 63, w = tid >> 6;
  const int quad = lane >> 4, l15 = lane & 15;
  const int wstart = w * 256;

  const size_t base = (size_t)bh * SEQ * DK;
  const ushort* Qp = Qh + base + (size_t)(q0 + l15) * DK + quad * 8;
  const f16x8 aq0 = *(const f16x8*)Qp;
  const f16x8 aq1 = *(const f16x8*)(Qp + 32);

  // ---- QK^T: 16 x 256 score strip in registers (C layout: row=quad*4+r, col=t*16+l15) ----
  f32x4 sc[16];
#pragma unroll
  for (int t = 0; t < 16; ++t) sc[t] = f32x4{0.f, 0.f, 0.f, 0.f};

  const ushort* Kp = Kh + base + (size_t)(wstart + l15) * DK + quad * 8;
#pragma unroll
  for (int t = 0; t < 16; ++t) {
    const ushort* kp = Kp + (size_t)(t * 16) * DK;
    const f16x8 b0 = *(const f16x8*)kp;
    const f16x8 b1 = *(const f16x8*)(kp + 32);
    sc[t] = __builtin_amdgcn_mfma_f32_16x16x32_f16(aq0, b0, sc[t], 0, 0, 0);
    sc[t] = __builtin_amdgcn_mfma_f32_16x16x32_f16(aq1, b1, sc[t], 0, 0, 0);
  }

  // ---- softmax ----
  __shared__ float redm[8][16];
  __shared__ float reds[8][16];
  constexpr float scale = 0.125f;  // 1/sqrt(64)

  float mrow[4];
#pragma unroll
  for (int r = 0; r < 4; ++r) {
    float v = sc[0][r];
#pragma unroll
    for (int t = 1; t < 16; ++t) v = fmaxf(v, sc[t][r]);
#pragma unroll
    for (int off = 1; off < 16; off <<= 1) v = fmaxf(v, __shfl_xor(v, off));
    if (l15 == 0) redm[w][quad * 4 + r] = v;
  }
  __syncthreads();
#pragma unroll
  for (int r = 0; r < 4; ++r) {
    const int row = quad * 4 + r;
    float m = redm[0][row];
#pragma unroll
    for (int wi = 1; wi < 8; ++wi) m = fmaxf(m, redm[wi][row]);
    mrow[r] = m;
  }
#pragma unroll
  for (int r = 0; r < 4; ++r) {
    float s = 0.f;
#pragma unroll
    for (int t = 0; t < 16; ++t) {
      const float e = __expf((sc[t][r] - mrow[r]) * scale);
      sc[t][r] = e;
      s += e;
    }
#pragma unroll
    for (int off = 1; off < 16; off <<= 1) s += __shfl_xor(s, off);
    if (l15 == 0) reds[w][quad * 4 + r] = s;
  }
  __syncthreads();
  float inv[4];
#pragma unroll
  for (int r = 0; r < 4; ++r) {
    const int row = quad * 4 + r;
    float s = reds[0][row];
#pragma unroll
    for (int wi = 1; wi < 8; ++wi) s += reds[wi][row];
    inv[r] = 1.f / s;
  }

  // ---- p store (nontemporal) + PV accumulate ----
  float* Pb = P + ((size_t)bh * SEQ + q0) * SEQ + wstart;
  __shared__ ushort Pl[8][16 * 40];  // per-wave P chunk in A-frag layout
  const ushort* Vb = Vt + (size_t)bh * DK * SEQ + wstart;
  f32x4 xacc[4];
#pragma unroll
  for (int dt = 0; dt < 4; ++dt) xacc[dt] = f32x4{0.f, 0.f, 0.f, 0.f};

#pragma unroll
  for (int c = 0; c < 8; ++c) {  // 32-col chunks
#pragma unroll
    for (int t2 = 0; t2 < 2; ++t2) {
      const int t = c * 2 + t2;
#pragma unroll
      for (int r = 0; r < 4; ++r) {
        const float p = sc[t][r] * inv[r];
        __builtin_nontemporal_store(p, &Pb[(size_t)(quad * 4 + r) * SEQ + t * 16 + l15]);
        Pl[w][(quad * 4 + r) * 40 + t2 * 16 + l15] = f2h_bits(p);
      }
    }
    const f16x8 pa = *(const f16x8*)&Pl[w][l15 * 40 + quad * 8];
#pragma unroll
    for (int dt = 0; dt < 4; ++dt) {
      const f16x8 bv = *(const f16x8*)(Vb + (size_t)(dt * 16 + l15) * SEQ + c * 32 + quad * 8);
      xacc[dt] = __builtin_amdgcn_mfma_f32_16x16x32_f16(pa, bv, xacc[dt], 0, 0, 0);
    }
  }

  // ---- reduce x across 8 waves, store merged [b,s,h*64+d] f16 ----
  __shared__ float xred[8][16 * 64];  // 32 KB
#pragma unroll
  for (int dt = 0; dt < 4; ++dt)
#pragma unroll
    for (int r = 0; r < 4; ++r)
      xred[w][(quad * 4 + r) * 64 + dt * 16 + l15] = xacc[dt][r];
  __syncthreads();
  {
    const int b = bh >> 4, h = bh & 15;
    const int e0 = tid * 2;
    const int row = e0 >> 6;
    const int d = e0 & 63;
    float s0 = 0.f, s1 = 0.f;
#pragma unroll
    for (int wi = 0; wi < 8; ++wi) {
      s0 += xred[wi][e0];
      s1 += xred[wi][e0 + 1];
    }
    ushort2 o;
    o.x = f2h_bits(s0);
    o.y = f2h_bits(s1);
    *(ushort2*)&Xm[((size_t)(b * SEQ + q0 + row)) * HID + h * DK + d] = o;
  }
}

// ---------------- launch ----------------
extern "C" void kernel_launch(void* const* d_in, const int* in_sizes, int n_in,
                              void* d_out, int out_size, void* d_ws, size_t ws_size,
                              hipStream_t stream) {
  const float* query = (const float*)d_in[0];
  const float* key   = (const float*)d_in[1];
  const float* value = (const float*)d_in[2];
  const float* Wq = (const float*)d_in[3];
  const float* bq = (const float*)d_in[4];
  const float* Wk = (const float*)d_in[5];
  const float* bk = (const float*)d_in[6];
  const float* Wv = (const float*)d_in[7];
  const float* bv = (const float*)d_in[8];
  const float* Wo = (const float*)d_in[9];
  const float* bo = (const float*)d_in[10];

  float* out  = (float*)d_out;
  float* pout = out + (size_t)MTOT * HID;  // p_attn section

  // workspace: exactly 32 MB
  ushort* Qhs = (ushort*)d_ws;             // [b,h,s,d] f16, 8 MB
  ushort* Khs = Qhs + 4194304;             // [b,h,s,d] f16, 8 MB
  ushort* Vtw = Khs + 4194304;             // [b,h,d,s] f16, 8 MB
  ushort* xm  = Vtw + 4194304;             // [b,s,h*64+d] f16, 8 MB

  gemm_qkv<<<dim3(8, 32, 3), 256, 0, stream>>>(query, key, value, Wq, Wk, Wv, bq, bk, bv, Qhs, Khs, Vtw);
  attn_kernel<<<dim3(128, 32), 512, 0, stream>>>(Qhs, Khs, Vtw, pout, xm);
  gemm_out<<<dim3(8, 32), 256, 0, stream>>>(xm, Wo, bo, out);
}

// Round 3
// 857.016 us; speedup vs baseline: 1.0623x; 1.0303x over previous
//
#include <hip/hip_runtime.h>
#include <hip/hip_fp16.h>
#include <stdint.h>

typedef _Float16 f16x8 __attribute__((ext_vector_type(8)));
typedef __fp16 h16x2 __attribute__((ext_vector_type(2)));
typedef float f32x4 __attribute__((ext_vector_type(4)));

#define NH   16
#define DK   64
#define SEQ  2048
#define HID  1024
#define MTOT 4096   // B*S

__device__ __forceinline__ ushort f2h_bits(float f) {
  union { __half h; ushort u; } cv;
  cv.h = __float2half(f);
  return cv.u;
}

__device__ __forceinline__ void lds_load16(const void* g, void* l) {
  __builtin_amdgcn_global_load_lds((const __attribute__((address_space(1))) uint32_t*)g,
                                   (__attribute__((address_space(3))) uint32_t*)l, 16, 0, 0);
}

__device__ __forceinline__ f16x8 cvt8(float4 v0, float4 v1) {
  union { f16x8 v; h16x2 p[4]; } u;
  u.p[0] = __builtin_amdgcn_cvt_pkrtz(v0.x, v0.y);
  u.p[1] = __builtin_amdgcn_cvt_pkrtz(v0.z, v0.w);
  u.p[2] = __builtin_amdgcn_cvt_pkrtz(v1.x, v1.y);
  u.p[3] = __builtin_amdgcn_cvt_pkrtz(v1.z, v1.w);
  return u.v;
}

// ---------------- f32 -> f16 conversion prepass ----------------
// Converts q,k,v (4.19M elems each) + Wq,Wk,Wv (1.05M each) into one contiguous f16
// scratch region (first 30 MB of the pout output section -- dead until attn_kernel
// overwrites all of it). Same cvt_pkrtz rounding as the old in-GEMM staging, so
// numerics are identical; GEMM panel re-reads then move half the bytes.
__global__ __launch_bounds__(256) void cvt6(const float* __restrict__ q, const float* __restrict__ k,
                                            const float* __restrict__ v, const float* __restrict__ wq,
                                            const float* __restrict__ wk, const float* __restrict__ wv,
                                            ushort* __restrict__ dst) {
  const size_t e = ((size_t)blockIdx.x * 256 + threadIdx.x) * 8;
  const float* s;
  size_t off;
  if (e < 4194304)       { s = q;  off = e; }
  else if (e < 8388608)  { s = k;  off = e - 4194304; }
  else if (e < 12582912) { s = v;  off = e - 8388608; }
  else if (e < 13631488) { s = wq; off = e - 12582912; }
  else if (e < 14680064) { s = wk; off = e - 13631488; }
  else                   { s = wv; off = e - 14680064; }
  const float4 v0 = *(const float4*)(s + off);
  const float4 v1 = *(const float4*)(s + off + 4);
  *(f16x8*)(dst + e) = cvt8(v0, v1);
}

// ---------------- NT GEMM: Y[m,n] = sum_k A[m,k]*W[n,k] + bias[n] ----------------
// 128x128 tile, BK=64, 4 waves (2x2), each wave 64x64 via 4x4 MFMA 16x16x32 f16.
// LDS layout XOR-swizzled: LDS[row][c] = SRC[row][c ^ (row&7)] -> conflict-light ds_read_b128.
// AF32/BF32 false: f16 source staged via global_load_lds width-16 (pre-swizzled source addr).
// mode 0: f16 out head-split [b,h,s,d]; mode 1: f32 row-major; mode 2: f16 [b,h,d,s] (V transposed).
template <bool AF32, bool BF32>
__device__ __forceinline__ void gemm_body(int mode, const void* __restrict__ Ap, const void* __restrict__ Bp,
                                          const float* __restrict__ bias, void* __restrict__ Out) {
  constexpr int K = 1024, N = 1024;
  __shared__ ushort As[128 * 64];
  __shared__ ushort Bs[128 * 64];
  const int tid = threadIdx.x;
  const int lane = tid & 63;
  const int w = tid >> 6;
  const int wr = w >> 1, wc = w & 1;
  const int bM = blockIdx.y * 128, bN = blockIdx.x * 128;
  const int srow = lane >> 3;                // row within 8-row group
  const int c8 = lane & 7;                   // chunk within row
  const int schunk = (c8 ^ srow) * 8;        // swizzled source chunk (elements)
  const int l15 = lane & 15, quad = lane >> 4;

  f32x4 acc[4][4];
#pragma unroll
  for (int i = 0; i < 4; ++i)
#pragma unroll
    for (int j = 0; j < 4; ++j) acc[i][j] = f32x4{0.f, 0.f, 0.f, 0.f};

  for (int k0 = 0; k0 < K; k0 += 64) {
#pragma unroll
    for (int j = 0; j < 4; ++j) {
      const int row = w * 32 + j * 8 + srow;
      if (AF32) {
        const float* src = (const float*)Ap + (size_t)(bM + row) * K + k0 + schunk;
        float4 v0 = *(const float4*)src;
        float4 v1 = *(const float4*)(src + 4);
        *(f16x8*)&As[row * 64 + c8 * 8] = cvt8(v0, v1);
      } else {
        lds_load16((const ushort*)Ap + (size_t)(bM + w * 32 + srow) * K + k0 + schunk + (size_t)(j * 8) * K,
                   &As[(w * 32 + j * 8) * 64]);
      }
      if (BF32) {
        const float* src = (const float*)Bp + (size_t)(bN + row) * K + k0 + schunk;
        float4 v0 = *(const float4*)src;
        float4 v1 = *(const float4*)(src + 4);
        *(f16x8*)&Bs[row * 64 + c8 * 8] = cvt8(v0, v1);
      } else {
        lds_load16((const ushort*)Bp + (size_t)(bN + w * 32 + srow) * K + k0 + schunk + (size_t)(j * 8) * K,
                   &Bs[(w * 32 + j * 8) * 64]);
      }
    }
    __syncthreads();
#pragma unroll
    for (int ks = 0; ks < 2; ++ks) {
      const int q = ks * 4 + quad;
      f16x8 af[4], bfr[4];
#pragma unroll
      for (int i = 0; i < 4; ++i) {
        const int m = wr * 64 + i * 16 + l15;
        af[i] = *(const f16x8*)&As[m * 64 + ((q ^ (m & 7)) * 8)];
        const int n = wc * 64 + i * 16 + l15;
        bfr[i] = *(const f16x8*)&Bs[n * 64 + ((q ^ (n & 7)) * 8)];
      }
#pragma unroll
      for (int i = 0; i < 4; ++i)
#pragma unroll
        for (int j = 0; j < 4; ++j)
          acc[i][j] = __builtin_amdgcn_mfma_f32_16x16x32_f16(af[i], bfr[j], acc[i][j], 0, 0, 0);
    }
    __syncthreads();
  }

  if (mode == 1) {
    float* O = (float*)Out;
#pragma unroll
    for (int j = 0; j < 4; ++j) {
      const int n = bN + wc * 64 + j * 16 + l15;
      const float bv = bias[n];
#pragma unroll
      for (int i = 0; i < 4; ++i) {
        const int mbase = bM + wr * 64 + i * 16 + quad * 4;
#pragma unroll
        for (int r = 0; r < 4; ++r)
          O[(size_t)(mbase + r) * N + n] = acc[i][j][r] + bv;
      }
    }
  } else if (mode == 0) {
    ushort* O = (ushort*)Out;
#pragma unroll
    for (int j = 0; j < 4; ++j) {
      const int n = bN + wc * 64 + j * 16 + l15;
      const int h = n >> 6, d = n & 63;
      const float bv = bias[n];
#pragma unroll
      for (int i = 0; i < 4; ++i) {
        const int mbase = bM + wr * 64 + i * 16 + quad * 4;
        const int b = mbase >> 11;
#pragma unroll
        for (int r = 0; r < 4; ++r) {
          const int s = (mbase + r) & 2047;
          O[((size_t)((b * NH + h) * SEQ + s)) * DK + d] = f2h_bits(acc[i][j][r] + bv);
        }
      }
    }
  } else {  // mode 2: V transposed [b,h,d,s]
    ushort* O = (ushort*)Out;
#pragma unroll
    for (int j = 0; j < 4; ++j) {
      const int n = bN + wc * 64 + j * 16 + l15;
      const int h = n >> 6, d = n & 63;
      const float bv = bias[n];
#pragma unroll
      for (int i = 0; i < 4; ++i) {
        const int mbase = bM + wr * 64 + i * 16 + quad * 4;
        const int b = mbase >> 11, s = mbase & 2047;
        ushort4 o;
        o.x = f2h_bits(acc[i][j][0] + bv);
        o.y = f2h_bits(acc[i][j][1] + bv);
        o.z = f2h_bits(acc[i][j][2] + bv);
        o.w = f2h_bits(acc[i][j][3] + bv);
        *(ushort4*)&O[((size_t)((b * NH + h) * DK + d)) * SEQ + s] = o;
      }
    }
  }
}

__global__ __launch_bounds__(256) void gemm_qkv(const ushort* qf, const ushort* kf, const ushort* vf,
                                                const ushort* wqf, const ushort* wkf, const ushort* wvf,
                                                const float* bq, const float* bk, const float* bv,
                                                ushort* oq, ushort* ok, ushort* ov) {
  const int z = blockIdx.z;
  const ushort* A = z == 0 ? qf : (z == 1 ? kf : vf);
  const ushort* W = z == 0 ? wqf : (z == 1 ? wkf : wvf);
  const float* bb = z == 0 ? bq : (z == 1 ? bk : bv);
  ushort* O = z == 0 ? oq : (z == 1 ? ok : ov);
  gemm_body<false, false>(z == 2 ? 2 : 0, A, W, bb, O);
}

__global__ __launch_bounds__(256) void gemm_out(const ushort* A, const float* W, const float* b, float* O) {
  gemm_body<false, true>(1, A, W, b, O);
}

// ---------------- attention ----------------
// block = (bh, 16 q-rows), 512 threads = 8 waves; wave w owns K-cols [w*256, w*256+256).
// Scores strip 16x256 per wave in registers (sc[16] = 64 VGPRs).
// XCD-aware chunked work remap (kept from R1: neutral but harmless, gives each XCD a
// 4-head / 2 MB K/V working set inside its private L2).
__global__ __launch_bounds__(512, 4) void attn_kernel(const ushort* __restrict__ Qh, const ushort* __restrict__ Kh,
                                                      const ushort* __restrict__ Vt, float* __restrict__ P,
                                                      ushort* __restrict__ Xm) {
  const int lin = blockIdx.y * 128 + blockIdx.x;   // hardware dispatch order
  const int work = (lin & 7) * 512 + (lin >> 3);   // chunked per-XCD remap (bijective, 4096%8==0)
  const int bh = work >> 7;        // 0..31
  const int q0 = (work & 127) * 16;  // q-tile start
  const int tid = threadIdx.x;
  const int lane = tid & 63, w = tid >> 6;
  const int quad = lane >> 4, l15 = lane & 15;
  const int wstart = w * 256;

  const size_t base = (size_t)bh * SEQ * DK;
  const ushort* Qp = Qh + base + (size_t)(q0 + l15) * DK + quad * 8;
  const f16x8 aq0 = *(const f16x8*)Qp;
  const f16x8 aq1 = *(const f16x8*)(Qp + 32);

  // ---- QK^T: 16 x 256 score strip in registers (C layout: row=quad*4+r, col=t*16+l15) ----
  f32x4 sc[16];
#pragma unroll
  for (int t = 0; t < 16; ++t) sc[t] = f32x4{0.f, 0.f, 0.f, 0.f};

  const ushort* Kp = Kh + base + (size_t)(wstart + l15) * DK + quad * 8;
#pragma unroll
  for (int t = 0; t < 16; ++t) {
    const ushort* kp = Kp + (size_t)(t * 16) * DK;
    const f16x8 b0 = *(const f16x8*)kp;
    const f16x8 b1 = *(const f16x8*)(kp + 32);
    sc[t] = __builtin_amdgcn_mfma_f32_16x16x32_f16(aq0, b0, sc[t], 0, 0, 0);
    sc[t] = __builtin_amdgcn_mfma_f32_16x16x32_f16(aq1, b1, sc[t], 0, 0, 0);
  }

  // ---- softmax ----
  __shared__ float redm[8][16];
  __shared__ float reds[8][16];
  constexpr float scale = 0.125f;  // 1/sqrt(64)

  float mrow[4];
#pragma unroll
  for (int r = 0; r < 4; ++r) {
    float v = sc[0][r];
#pragma unroll
    for (int t = 1; t < 16; ++t) v = fmaxf(v, sc[t][r]);
#pragma unroll
    for (int off = 1; off < 16; off <<= 1) v = fmaxf(v, __shfl_xor(v, off));
    if (l15 == 0) redm[w][quad * 4 + r] = v;
  }
  __syncthreads();
#pragma unroll
  for (int r = 0; r < 4; ++r) {
    const int row = quad * 4 + r;
    float m = redm[0][row];
#pragma unroll
    for (int wi = 1; wi < 8; ++wi) m = fmaxf(m, redm[wi][row]);
    mrow[r] = m;
  }
#pragma unroll
  for (int r = 0; r < 4; ++r) {
    float s = 0.f;
#pragma unroll
    for (int t = 0; t < 16; ++t) {
      const float e = __expf((sc[t][r] - mrow[r]) * scale);
      sc[t][r] = e;
      s += e;
    }
#pragma unroll
    for (int off = 1; off < 16; off <<= 1) s += __shfl_xor(s, off);
    if (l15 == 0) reds[w][quad * 4 + r] = s;
  }
  __syncthreads();
  float inv[4];
#pragma unroll
  for (int r = 0; r < 4; ++r) {
    const int row = quad * 4 + r;
    float s = reds[0][row];
#pragma unroll
    for (int wi = 1; wi < 8; ++wi) s += reds[wi][row];
    inv[r] = 1.f / s;
  }

  // ---- p store (nontemporal) + PV accumulate ----
  float* Pb = P + ((size_t)bh * SEQ + q0) * SEQ + wstart;
  __shared__ ushort Pl[8][16 * 40];  // per-wave P chunk in A-frag layout
  const ushort* Vb = Vt + (size_t)bh * DK * SEQ + wstart;
  f32x4 xacc[4];
#pragma unroll
  for (int dt = 0; dt < 4; ++dt) xacc[dt] = f32x4{0.f, 0.f, 0.f, 0.f};

#pragma unroll
  for (int c = 0; c < 8; ++c) {  // 32-col chunks
#pragma unroll
    for (int t2 = 0; t2 < 2; ++t2) {
      const int t = c * 2 + t2;
#pragma unroll
      for (int r = 0; r < 4; ++r) {
        const float p = sc[t][r] * inv[r];
        __builtin_nontemporal_store(p, &Pb[(size_t)(quad * 4 + r) * SEQ + t * 16 + l15]);
        Pl[w][(quad * 4 + r) * 40 + t2 * 16 + l15] = f2h_bits(p);
      }
    }
    const f16x8 pa = *(const f16x8*)&Pl[w][l15 * 40 + quad * 8];
#pragma unroll
    for (int dt = 0; dt < 4; ++dt) {
      const f16x8 bv = *(const f16x8*)(Vb + (size_t)(dt * 16 + l15) * SEQ + c * 32 + quad * 8);
      xacc[dt] = __builtin_amdgcn_mfma_f32_16x16x32_f16(pa, bv, xacc[dt], 0, 0, 0);
    }
  }

  // ---- reduce x across 8 waves, store merged [b,s,h*64+d] f16 ----
  __shared__ float xred[8][16 * 64];  // 32 KB
#pragma unroll
  for (int dt = 0; dt < 4; ++dt)
#pragma unroll
    for (int r = 0; r < 4; ++r)
      xred[w][(quad * 4 + r) * 64 + dt * 16 + l15] = xacc[dt][r];
  __syncthreads();
  {
    const int b = bh >> 4, h = bh & 15;
    const int e0 = tid * 2;
    const int row = e0 >> 6;
    const int d = e0 & 63;
    float s0 = 0.f, s1 = 0.f;
#pragma unroll
    for (int wi = 0; wi < 8; ++wi) {
      s0 += xred[wi][e0];
      s1 += xred[wi][e0 + 1];
    }
    ushort2 o;
    o.x = f2h_bits(s0);
    o.y = f2h_bits(s1);
    *(ushort2*)&Xm[((size_t)(b * SEQ + q0 + row)) * HID + h * DK + d] = o;
  }
}

// ---------------- launch ----------------
extern "C" void kernel_launch(void* const* d_in, const int* in_sizes, int n_in,
                              void* d_out, int out_size, void* d_ws, size_t ws_size,
                              hipStream_t stream) {
  const float* query = (const float*)d_in[0];
  const float* key   = (const float*)d_in[1];
  const float* value = (const float*)d_in[2];
  const float* Wq = (const float*)d_in[3];
  const float* bq = (const float*)d_in[4];
  const float* Wk = (const float*)d_in[5];
  const float* bk = (const float*)d_in[6];
  const float* Wv = (const float*)d_in[7];
  const float* bv = (const float*)d_in[8];
  const float* Wo = (const float*)d_in[9];
  const float* bo = (const float*)d_in[10];

  float* out  = (float*)d_out;
  float* pout = out + (size_t)MTOT * HID;  // p_attn section

  // workspace: exactly 32 MB
  ushort* Qhs = (ushort*)d_ws;             // [b,h,s,d] f16, 8 MB
  ushort* Khs = Qhs + 4194304;             // [b,h,s,d] f16, 8 MB
  ushort* Vtw = Khs + 4194304;             // [b,h,d,s] f16, 8 MB
  ushort* xm  = Vtw + 4194304;             // [b,s,h*64+d] f16, 8 MB

  // f16 scratch in the (not-yet-written) pout region: 30 MB of 512 MB.
  // attn_kernel later overwrites every byte of pout, so this is dead storage by then.
  ushort* cv  = (ushort*)pout;
  ushort* qf  = cv;                         // 4.19M elems
  ushort* kf  = cv + 4194304;
  ushort* vf  = cv + 8388608;
  ushort* wqf = cv + 12582912;              // 1.05M elems
  ushort* wkf = cv + 13631488;
  ushort* wvf = cv + 14680064;

  cvt6<<<7680, 256, 0, stream>>>(query, key, value, Wq, Wk, Wv, cv);
  gemm_qkv<<<dim3(8, 32, 3), 256, 0, stream>>>(qf, kf, vf, wqf, wkf, wvf, bq, bk, bv, Qhs, Khs, Vtw);
  attn_kernel<<<dim3(128, 32), 512, 0, stream>>>(Qhs, Khs, Vtw, pout, xm);
  gemm_out<<<dim3(8, 32), 256, 0, stream>>>(xm, Wo, bo, out);
}